// Round 12
// baseline (119.995 us; speedup 1.0000x reference)
//
#include <hip/hip_runtime.h>
#include <hip/hip_bf16.h>

#define N_NODES 10000
#define N_EDGES 320000
#define D 256        // D_IN == D_OUT
#define K_TOT 512    // 2*D
#define CAP 128      // per-node bucket capacity (max Poisson(32) degree ~65)

typedef __attribute__((ext_vector_type(8))) short bf16x8;
typedef __attribute__((ext_vector_type(4))) float f32x4;

__device__ __forceinline__ float bf2f(unsigned short u) {
  return __uint_as_float(((unsigned int)u) << 16);
}
__device__ __forceinline__ unsigned short f2bf(float f) {
  unsigned int x = __float_as_uint(f);
  unsigned int r = (x + 0x7fffu + ((x >> 16) & 1u)) >> 16;   // RNE
  return (unsigned short)r;
}

// ---------------------------------------------------------------------------
// Pass 0: feat -> hcat[:,256:512] (bf16), W -> Wb (bf16), zero cursor+done.
// ---------------------------------------------------------------------------
#define FEAT_VECS (N_NODES * D / 8)         // 320000
#define W_VECS    (D * K_TOT / 8)           // 16384
#define ZERO_VECS ((N_NODES + 160) / 4)     // 2540 int4: cursor[10000]+done[160]
__global__ __launch_bounds__(256) void tobf16_kernel(
    const float* __restrict__ feat, const float* __restrict__ W,
    unsigned short* __restrict__ hcat, unsigned short* __restrict__ Wb,
    int* __restrict__ cursor /* done[160] follows cursor contiguously */) {
  int gid = blockIdx.x * 256 + threadIdx.x;
  const float* srcp;
  unsigned short* dstp;
  if (gid < FEAT_VECS) {
    int row = gid >> 5;          // 32 vec8 per 256-row
    int v = gid & 31;
    srcp = feat + (size_t)row * D + v * 8;
    dstp = hcat + (size_t)row * K_TOT + D + v * 8;
  } else if (gid < FEAT_VECS + W_VECS) {
    int g = gid - FEAT_VECS;
    int row = g >> 6;            // 64 vec8 per 512-row
    int v = g & 63;
    srcp = W + (size_t)row * K_TOT + v * 8;
    dstp = Wb + (size_t)row * K_TOT + v * 8;
  } else if (gid < FEAT_VECS + W_VECS + ZERO_VECS) {
    int g = gid - (FEAT_VECS + W_VECS);
    reinterpret_cast<int4*>(cursor)[g] = make_int4(0, 0, 0, 0);
    return;
  } else {
    return;
  }
  float4 a = reinterpret_cast<const float4*>(srcp)[0];
  float4 b = reinterpret_cast<const float4*>(srcp)[1];
  reinterpret_cast<ushort4*>(dstp)[0] =
      make_ushort4(f2bf(a.x), f2bf(a.y), f2bf(a.z), f2bf(a.w));
  reinterpret_cast<ushort4*>(dstp)[1] =
      make_ushort4(f2bf(b.x), f2bf(b.y), f2bf(b.z), f2bf(b.w));
}

// ---------------------------------------------------------------------------
// Pass 1: atomic-append edges into per-dst buckets. 2 edges per thread.
// ---------------------------------------------------------------------------
__global__ __launch_bounds__(256) void append_kernel(const int* __restrict__ src,
                                                     const int* __restrict__ dst,
                                                     const float* __restrict__ ew,
                                                     int* __restrict__ cursor,
                                                     int2* __restrict__ bucket) {
  int i = (blockIdx.x * 256 + threadIdx.x) * 2;
  if (i + 1 < N_EDGES) {
    int2 s2 = *reinterpret_cast<const int2*>(src + i);
    int2 d2 = *reinterpret_cast<const int2*>(dst + i);
    float2 w2 = *reinterpret_cast<const float2*>(ew + i);
    int pos0 = atomicAdd(&cursor[d2.x], 1);
    if (pos0 < CAP)
      bucket[(size_t)d2.x * CAP + pos0] = make_int2(s2.x, __float_as_int(w2.x));
    int pos1 = atomicAdd(&cursor[d2.y], 1);
    if (pos1 < CAP)
      bucket[(size_t)d2.y * CAP + pos1] = make_int2(s2.y, __float_as_int(w2.y));
  } else if (i < N_EDGES) {
    int d = dst[i];
    int pos = atomicAdd(&cursor[d], 1);
    if (pos < CAP)
      bucket[(size_t)d * CAP + pos] = make_int2(src[i], __float_as_int(ew[i]));
  }
}

// ---------------------------------------------------------------------------
// Pass 2 (FUSED): blocks 0..2499 = agg (4 nodes each; release-flag per
// 64-node row-tile); blocks 2500..3127 = gemm tiles that do the feat-half K
// first, acquire-spin on done[rowtile], then the h_neigh-half K.
// Forward progress: only the 628 gemm blocks ever spin; resident capacity
// (18.4KB LDS -> 8 blocks/CU -> >=2048 slots) exceeds that, so agg blocks
// always get slots regardless of dispatch order.
// ---------------------------------------------------------------------------
#define AGG_BLKS 2500
#define GBM 64
#define GBN 64
#define GBK 64
#define LPAD 72     // LDS row stride in bf16 elems (+8 pad)
#define RTILES 157  // ceil(10000/64)

__global__ __launch_bounds__(256) void aggemm_kernel(
    const int* __restrict__ cursor, const int2* __restrict__ bucket,
    unsigned short* __restrict__ hcat, const unsigned short* __restrict__ Wb,
    const float* __restrict__ bias, float* __restrict__ out,
    int* __restrict__ done) {
  __shared__ unsigned short As[GBM][LPAD];
  __shared__ unsigned short Bs[GBN][LPAD];

  if (blockIdx.x < AGG_BLKS) {
    // ---------------- agg: node = blk*4 + wave, lane = 4 channels -----------
    int node = (blockIdx.x << 2) + (threadIdx.x >> 6);
    int lane = threadIdx.x & 63;
    int cnt = cursor[node];
    int end = min(cnt, CAP);
    const int2* bk = bucket + (size_t)node * CAP;
    const unsigned short* fb = hcat + D + (size_t)lane * 4;
    float acc0 = 0.f, acc1 = 0.f, acc2 = 0.f, acc3 = 0.f;
    int i = 0;

#define GATHER2(p, va, vb)                                                     \
    va = *reinterpret_cast<const ushort4*>(fb + (size_t)(p).x * K_TOT);        \
    vb = *reinterpret_cast<const ushort4*>(fb + (size_t)(p).z * K_TOT);
#define ACC1(v, wgt)                                                           \
    acc0 += bf2f((v).x) * (wgt); acc1 += bf2f((v).y) * (wgt);                  \
    acc2 += bf2f((v).z) * (wgt); acc3 += bf2f((v).w) * (wgt);
#define ACCP(p, va, vb)                                                        \
    { float wa_ = __int_as_float((p).y), wb_ = __int_as_float((p).w);          \
      ACC1(va, wa_) ACC1(vb, wb_) }

    for (; i + 8 <= end; i += 8) {
      int4 p0 = *reinterpret_cast<const int4*>(bk + i);
      int4 p1 = *reinterpret_cast<const int4*>(bk + i + 2);
      int4 p2 = *reinterpret_cast<const int4*>(bk + i + 4);
      int4 p3 = *reinterpret_cast<const int4*>(bk + i + 6);
      ushort4 v0, v1, v2, v3, v4, v5, v6, v7;
      GATHER2(p0, v0, v1) GATHER2(p1, v2, v3) GATHER2(p2, v4, v5) GATHER2(p3, v6, v7)
      ACCP(p0, v0, v1) ACCP(p1, v2, v3) ACCP(p2, v4, v5) ACCP(p3, v6, v7)
    }
    for (; i < end; ++i) {
      int2 sw = bk[i];
      ushort4 v = *reinterpret_cast<const ushort4*>(fb + (size_t)sw.x * K_TOT);
      float wgt = __int_as_float(sw.y);
      ACC1(v, wgt)
    }
#undef GATHER2
#undef ACC1
#undef ACCP

    float inv = 1.0f / fmaxf((float)cnt, 1.0f);
    ushort4 o = make_ushort4(f2bf(acc0 * inv), f2bf(acc1 * inv),
                             f2bf(acc2 * inv), f2bf(acc3 * inv));
    *reinterpret_cast<ushort4*>(hcat + (size_t)node * K_TOT + lane * 4) = o;

    __syncthreads();   // all 4 waves' stores issued & drained
    if (threadIdx.x == 0) {
      __hip_atomic_fetch_add(&done[blockIdx.x >> 4], 1,
                             __ATOMIC_RELEASE, __HIP_MEMORY_SCOPE_AGENT);
    }
    return;
  }

  // ---------------- gemm tile ------------------------------------------------
  int bid = blockIdx.x - AGG_BLKS;
  int r, c;
  if (bid < 608) {                 // 19 groups of 8 row-tiles x 4 col-tiles
    int g = bid >> 5;
    int w8 = bid & 31;
    r = g * 8 + (w8 & 7);
    c = w8 >> 3;
  } else {                         // tail: row-tiles 152..156
    int w8 = bid - 608;
    r = 152 + w8 % 5;
    c = w8 / 5;
  }
  int row0 = r * GBM;
  int col0 = c * GBN;

  int t = threadIdx.x;
  int lane = t & 63;
  int w = t >> 6;
  int wr = w >> 1;      // 0..1
  int wc = w & 1;       // 0..1
  int lhi = lane >> 4;  // 0..3
  int llo = lane & 15;

  f32x4 acc[2][2];
  #pragma unroll
  for (int m = 0; m < 2; ++m)
    #pragma unroll
    for (int n = 0; n < 2; ++n) acc[m][n] = (f32x4){0.f, 0.f, 0.f, 0.f};

#define GEMM_KSTEP(k0)                                                         \
  {                                                                            \
    _Pragma("unroll")                                                          \
    for (int it = 0; it < 2; ++it) {                                           \
      int idx = t + it * 256;                                                  \
      int rr = idx >> 3;                                                       \
      int kv = (idx & 7) * 8;                                                  \
      int row = row0 + rr;                                                     \
      uint4 v = make_uint4(0, 0, 0, 0);                                        \
      if (row < N_NODES)                                                       \
        v = *reinterpret_cast<const uint4*>(hcat + (size_t)row * K_TOT + (k0) + kv); \
      *reinterpret_cast<uint4*>(&As[rr][kv]) = v;                              \
    }                                                                          \
    _Pragma("unroll")                                                          \
    for (int it = 0; it < 2; ++it) {                                           \
      int idx = t + it * 256;                                                  \
      int cc = idx >> 3;                                                       \
      int kv = (idx & 7) * 8;                                                  \
      uint4 v = *reinterpret_cast<const uint4*>(                               \
          Wb + (size_t)(col0 + cc) * K_TOT + (k0) + kv);                       \
      *reinterpret_cast<uint4*>(&Bs[cc][kv]) = v;                              \
    }                                                                          \
    __syncthreads();                                                           \
    _Pragma("unroll")                                                          \
    for (int ks = 0; ks < 2; ++ks) {                                           \
      int ak = ks * 32 + lhi * 8;                                              \
      bf16x8 a[2], b[2];                                                       \
      _Pragma("unroll")                                                        \
      for (int m = 0; m < 2; ++m)                                              \
        a[m] = *reinterpret_cast<const bf16x8*>(&As[wr * 32 + m * 16 + llo][ak]); \
      _Pragma("unroll")                                                        \
      for (int n = 0; n < 2; ++n)                                              \
        b[n] = *reinterpret_cast<const bf16x8*>(&Bs[wc * 32 + n * 16 + llo][ak]); \
      _Pragma("unroll")                                                        \
      for (int m = 0; m < 2; ++m)                                              \
        _Pragma("unroll")                                                      \
        for (int n = 0; n < 2; ++n)                                            \
          acc[m][n] = __builtin_amdgcn_mfma_f32_16x16x32_bf16(a[m], b[n], acc[m][n], 0, 0, 0); \
    }                                                                          \
    __syncthreads();                                                           \
  }

  // feat-half K first (columns 256..511 of hcat: written in pass 0, ready)
  for (int k0 = D; k0 < K_TOT; k0 += GBK) GEMM_KSTEP(k0)

  // acquire-spin until this row-tile's agg blocks are done
  if (t == 0) {
    int target = min(16, AGG_BLKS - (r << 4));   // 16, or 4 for r==156
    while (__hip_atomic_load(&done[r], __ATOMIC_ACQUIRE,
                             __HIP_MEMORY_SCOPE_AGENT) < target)
      __builtin_amdgcn_s_sleep(8);
  }
  __syncthreads();

  // h_neigh-half K
  for (int k0 = 0; k0 < D; k0 += GBK) GEMM_KSTEP(k0)
#undef GEMM_KSTEP

  #pragma unroll
  for (int m = 0; m < 2; ++m) {
    #pragma unroll
    for (int n = 0; n < 2; ++n) {
      int col = col0 + wc * 32 + n * 16 + llo;
      float bv = bias[col];
      #pragma unroll
      for (int rr = 0; rr < 4; ++rr) {
        int orow = row0 + wr * 32 + m * 16 + lhi * 4 + rr;
        if (orow < N_NODES)
          out[(size_t)orow * D + col] = acc[m][n][rr] + bv;
      }
    }
  }
}

extern "C" void kernel_launch(void* const* d_in, const int* in_sizes, int n_in,
                              void* d_out, int out_size, void* d_ws, size_t ws_size,
                              hipStream_t stream) {
  const float* feat = (const float*)d_in[0];   // [10000,256]
  const float* ew   = (const float*)d_in[1];   // [320000,1]
  const float* W    = (const float*)d_in[2];   // [256,512]
  const float* bias = (const float*)d_in[3];   // [256]
  const int*   src  = (const int*)d_in[4];     // [320000]
  const int*   dst  = (const int*)d_in[5];     // [320000]
  float* out = (float*)d_out;                  // [10000,256]

  // workspace layout (cursor and done contiguous for one-range zeroing)
  char* ws = (char*)d_ws;
  unsigned short* hcat = (unsigned short*)ws;  ws += (size_t)N_NODES * K_TOT * sizeof(unsigned short); // 10.24 MB
  unsigned short* Wb   = (unsigned short*)ws;  ws += (size_t)D * K_TOT * sizeof(unsigned short);       // 0.26 MB
  int* cursor   = (int*)ws;                    ws += N_NODES * sizeof(int);
  int* done     = (int*)ws;                    ws += 160 * sizeof(int);
  int2* bucket  = (int2*)ws;                   ws += (size_t)N_NODES * CAP * sizeof(int2);             // 10.24 MB

  tobf16_kernel<<<(FEAT_VECS + W_VECS + ZERO_VECS + 255) / 256, 256, 0, stream>>>(
      feat, W, hcat, Wb, cursor);
  append_kernel<<<(N_EDGES / 2 + 255) / 256, 256, 0, stream>>>(src, dst, ew, cursor, bucket);
  aggemm_kernel<<<AGG_BLKS + RTILES * 4, 256, 0, stream>>>(
      cursor, bucket, hcat, Wb, bias, out, done);
}

// Round 13
// 86.084 us; speedup vs baseline: 1.3939x; 1.3939x over previous
//
#include <hip/hip_runtime.h>
#include <hip/hip_bf16.h>

#define N_NODES 10000
#define N_EDGES 320000
#define D 256        // D_IN == D_OUT
#define K_TOT 512    // 2*D
#define CAP 128      // per-node bucket capacity (max Poisson(32) degree ~65)

typedef __attribute__((ext_vector_type(8))) short bf16x8;
typedef __attribute__((ext_vector_type(4))) float f32x4;

__device__ __forceinline__ float bf2f(unsigned short u) {
  return __uint_as_float(((unsigned int)u) << 16);
}
__device__ __forceinline__ unsigned short f2bf(float f) {
  unsigned int x = __float_as_uint(f);
  unsigned int r = (x + 0x7fffu + ((x >> 16) & 1u)) >> 16;   // RNE
  return (unsigned short)r;
}

// ---------------------------------------------------------------------------
// Pass 0: feat -> featb (bf16, dense [10000][256]), W -> Wb (bf16),
// zero cursor.
// ---------------------------------------------------------------------------
#define FEAT_VECS (N_NODES * D / 8)     // 320000
#define W_VECS    (D * K_TOT / 8)       // 16384
#define CUR_VECS  (N_NODES / 4)         // 2500 (int4 zeroing)
__global__ __launch_bounds__(256) void tobf16_kernel(
    const float* __restrict__ feat, const float* __restrict__ W,
    unsigned short* __restrict__ featb, unsigned short* __restrict__ Wb,
    int* __restrict__ cursor) {
  int gid = blockIdx.x * 256 + threadIdx.x;
  const float* srcp;
  unsigned short* dstp;
  if (gid < FEAT_VECS) {
    srcp = feat + (size_t)gid * 8;
    dstp = featb + (size_t)gid * 8;
  } else if (gid < FEAT_VECS + W_VECS) {
    int g = gid - FEAT_VECS;
    srcp = W + (size_t)g * 8;
    dstp = Wb + (size_t)g * 8;
  } else if (gid < FEAT_VECS + W_VECS + CUR_VECS) {
    int g = gid - (FEAT_VECS + W_VECS);
    reinterpret_cast<int4*>(cursor)[g] = make_int4(0, 0, 0, 0);
    return;
  } else {
    return;
  }
  float4 a = reinterpret_cast<const float4*>(srcp)[0];
  float4 b = reinterpret_cast<const float4*>(srcp)[1];
  reinterpret_cast<ushort4*>(dstp)[0] =
      make_ushort4(f2bf(a.x), f2bf(a.y), f2bf(a.z), f2bf(a.w));
  reinterpret_cast<ushort4*>(dstp)[1] =
      make_ushort4(f2bf(b.x), f2bf(b.y), f2bf(b.z), f2bf(b.w));
}

// ---------------------------------------------------------------------------
// Pass 1: atomic-append edges into per-dst buckets. 2 edges per thread.
// ---------------------------------------------------------------------------
__global__ __launch_bounds__(256) void append_kernel(const int* __restrict__ src,
                                                     const int* __restrict__ dst,
                                                     const float* __restrict__ ew,
                                                     int* __restrict__ cursor,
                                                     int2* __restrict__ bucket) {
  int i = (blockIdx.x * 256 + threadIdx.x) * 2;
  if (i + 1 < N_EDGES) {
    int2 s2 = *reinterpret_cast<const int2*>(src + i);
    int2 d2 = *reinterpret_cast<const int2*>(dst + i);
    float2 w2 = *reinterpret_cast<const float2*>(ew + i);
    int pos0 = atomicAdd(&cursor[d2.x], 1);
    if (pos0 < CAP)
      bucket[(size_t)d2.x * CAP + pos0] = make_int2(s2.x, __float_as_int(w2.x));
    int pos1 = atomicAdd(&cursor[d2.y], 1);
    if (pos1 < CAP)
      bucket[(size_t)d2.y * CAP + pos1] = make_int2(s2.y, __float_as_int(w2.y));
  } else if (i < N_EDGES) {
    int d = dst[i];
    int pos = atomicAdd(&cursor[d], 1);
    if (pos < CAP)
      bucket[(size_t)d * CAP + pos] = make_int2(src[i], __float_as_int(ew[i]));
  }
}

// ---------------------------------------------------------------------------
// Pass 2 (FUSED, no cross-block deps): block b owns nodes [16b,16b+16).
// Phase A: wave w aggregates 4 nodes sequentially (lane = 4 channels,
//          8-deep gather pipeline) -> h_neigh bf16 into LDS only.
// Phase B: stage feat rows (bf16) into LDS -> A-tile [16][512] complete.
// Phase C: wave w computes cols [64w,64w+64): A-frag from LDS, B-frag direct
//          from L2-resident Wb (0.26 MB). MFMA k-order identical to R11.
// 625 blocks x 16 = 10000 exactly. LDS 33.3 KB.
// ---------------------------------------------------------------------------
#define LPAD2 520   // A-tile LDS row stride (520 us = 260 dw; rows advance 4 banks)

__global__ __launch_bounds__(256) void aggemm_kernel(
    const int* __restrict__ cursor, const int2* __restrict__ bucket,
    const unsigned short* __restrict__ featb, const unsigned short* __restrict__ Wb,
    const float* __restrict__ bias, float* __restrict__ out) {
  __shared__ unsigned short Ah[16][LPAD2];   // 33.3 KB

  int t = threadIdx.x;
  int w = t >> 6;
  int lane = t & 63;
  int node0 = blockIdx.x * 16;

  // ---------------- Phase A: aggregate 4 nodes per wave ----------------
  const unsigned short* fb = featb + (size_t)lane * 4;
  for (int j = 0; j < 4; ++j) {
    int local = (w << 2) + j;
    int node = node0 + local;
    int cnt = cursor[node];
    int end = min(cnt, CAP);
    const int2* bk = bucket + (size_t)node * CAP;
    float acc0 = 0.f, acc1 = 0.f, acc2 = 0.f, acc3 = 0.f;
    int i = 0;

#define GATHER2(p, va, vb)                                                     \
    va = *reinterpret_cast<const ushort4*>(fb + (size_t)(p).x * D);            \
    vb = *reinterpret_cast<const ushort4*>(fb + (size_t)(p).z * D);
#define ACC1(v, wgt)                                                           \
    acc0 += bf2f((v).x) * (wgt); acc1 += bf2f((v).y) * (wgt);                  \
    acc2 += bf2f((v).z) * (wgt); acc3 += bf2f((v).w) * (wgt);
#define ACCP(p, va, vb)                                                        \
    { float wa_ = __int_as_float((p).y), wb_ = __int_as_float((p).w);          \
      ACC1(va, wa_) ACC1(vb, wb_) }

    for (; i + 8 <= end; i += 8) {
      int4 p0 = *reinterpret_cast<const int4*>(bk + i);
      int4 p1 = *reinterpret_cast<const int4*>(bk + i + 2);
      int4 p2 = *reinterpret_cast<const int4*>(bk + i + 4);
      int4 p3 = *reinterpret_cast<const int4*>(bk + i + 6);
      ushort4 v0, v1, v2, v3, v4, v5, v6, v7;
      GATHER2(p0, v0, v1) GATHER2(p1, v2, v3) GATHER2(p2, v4, v5) GATHER2(p3, v6, v7)
      ACCP(p0, v0, v1) ACCP(p1, v2, v3) ACCP(p2, v4, v5) ACCP(p3, v6, v7)
    }
    for (; i < end; ++i) {
      int2 sw = bk[i];
      ushort4 v = *reinterpret_cast<const ushort4*>(fb + (size_t)sw.x * D);
      float wgt = __int_as_float(sw.y);
      ACC1(v, wgt)
    }
#undef GATHER2
#undef ACC1
#undef ACCP

    float inv = 1.0f / fmaxf((float)cnt, 1.0f);
    ushort4 o = make_ushort4(f2bf(acc0 * inv), f2bf(acc1 * inv),
                             f2bf(acc2 * inv), f2bf(acc3 * inv));
    *reinterpret_cast<ushort4*>(&Ah[local][lane * 4]) = o;
  }

  // ---------------- Phase B: stage feat half of the A-tile ----------------
  #pragma unroll
  for (int it = 0; it < 2; ++it) {
    int idx = t + it * 256;        // 0..511 = 16 rows x 32 vec8
    int r = idx >> 5;
    int v = idx & 31;
    uint4 x = *reinterpret_cast<const uint4*>(featb + (size_t)(node0 + r) * D + v * 8);
    *reinterpret_cast<uint4*>(&Ah[r][D + v * 8]) = x;
  }
  __syncthreads();

  // ---------------- Phase C: gemm, wave w owns 64 cols ----------------
  int lhi = lane >> 4;   // 0..3
  int llo = lane & 15;   // 0..15
  f32x4 acc[4];
  #pragma unroll
  for (int n = 0; n < 4; ++n) acc[n] = (f32x4){0.f, 0.f, 0.f, 0.f};

  const unsigned short* wb0 = Wb + (size_t)(w * 64 + llo) * K_TOT + lhi * 8;
  #pragma unroll
  for (int ks = 0; ks < 16; ++ks) {
    bf16x8 a = *reinterpret_cast<const bf16x8*>(&Ah[llo][ks * 32 + lhi * 8]);
    #pragma unroll
    for (int n = 0; n < 4; ++n) {
      bf16x8 b = *reinterpret_cast<const bf16x8*>(wb0 + (size_t)(n * 16) * K_TOT + ks * 32);
      acc[n] = __builtin_amdgcn_mfma_f32_16x16x32_bf16(a, b, acc[n], 0, 0, 0);
    }
  }

  #pragma unroll
  for (int n = 0; n < 4; ++n) {
    int col = w * 64 + n * 16 + llo;
    float bv = bias[col];
    #pragma unroll
    for (int r = 0; r < 4; ++r) {
      out[(size_t)(node0 + lhi * 4 + r) * D + col] = acc[n][r] + bv;
    }
  }
}

extern "C" void kernel_launch(void* const* d_in, const int* in_sizes, int n_in,
                              void* d_out, int out_size, void* d_ws, size_t ws_size,
                              hipStream_t stream) {
  const float* feat = (const float*)d_in[0];   // [10000,256]
  const float* ew   = (const float*)d_in[1];   // [320000,1]
  const float* W    = (const float*)d_in[2];   // [256,512]
  const float* bias = (const float*)d_in[3];   // [256]
  const int*   src  = (const int*)d_in[4];     // [320000]
  const int*   dst  = (const int*)d_in[5];     // [320000]
  float* out = (float*)d_out;                  // [10000,256]

  // workspace layout
  char* ws = (char*)d_ws;
  unsigned short* featb = (unsigned short*)ws; ws += (size_t)N_NODES * D * sizeof(unsigned short);   // 5.12 MB
  unsigned short* Wb    = (unsigned short*)ws; ws += (size_t)D * K_TOT * sizeof(unsigned short);     // 0.26 MB
  int* cursor   = (int*)ws;                    ws += N_NODES * sizeof(int);
  int2* bucket  = (int2*)ws;                   ws += (size_t)N_NODES * CAP * sizeof(int2);           // 10.24 MB

  tobf16_kernel<<<(FEAT_VECS + W_VECS + CUR_VECS + 255) / 256, 256, 0, stream>>>(
      feat, W, featb, Wb, cursor);
  append_kernel<<<(N_EDGES / 2 + 255) / 256, 256, 0, stream>>>(src, dst, ew, cursor, bucket);
  aggemm_kernel<<<N_NODES / 16, 256, 0, stream>>>(cursor, bucket, featb, Wb, bias, out);
}

// Round 14
// 80.928 us; speedup vs baseline: 1.4827x; 1.0637x over previous
//
#include <hip/hip_runtime.h>
#include <hip/hip_bf16.h>

#define N_NODES 10000
#define N_EDGES 320000
#define D 256        // D_IN == D_OUT
#define K_TOT 512    // 2*D
#define CAP 128      // per-node bucket capacity (max Poisson(32) degree ~65)

typedef __attribute__((ext_vector_type(8))) short bf16x8;
typedef __attribute__((ext_vector_type(4))) float f32x4;

__device__ __forceinline__ float bf2f(unsigned short u) {
  return __uint_as_float(((unsigned int)u) << 16);
}
__device__ __forceinline__ unsigned short f2bf(float f) {
  unsigned int x = __float_as_uint(f);
  unsigned int r = (x + 0x7fffu + ((x >> 16) & 1u)) >> 16;   // RNE
  return (unsigned short)r;
}

// ---------------------------------------------------------------------------
// Pass 0: feat -> featb (bf16 dense [10000][256]), W -> Wb (bf16), zero cursor.
// ---------------------------------------------------------------------------
#define FEAT_VECS (N_NODES * D / 8)     // 320000
#define W_VECS    (D * K_TOT / 8)       // 16384
#define CUR_VECS  (N_NODES / 4)         // 2500 (int4 zeroing)
__global__ __launch_bounds__(256) void tobf16_kernel(
    const float* __restrict__ feat, const float* __restrict__ W,
    unsigned short* __restrict__ featb, unsigned short* __restrict__ Wb,
    int* __restrict__ cursor) {
  int gid = blockIdx.x * 256 + threadIdx.x;
  const float* srcp;
  unsigned short* dstp;
  if (gid < FEAT_VECS) {
    srcp = feat + (size_t)gid * 8;
    dstp = featb + (size_t)gid * 8;
  } else if (gid < FEAT_VECS + W_VECS) {
    int g = gid - FEAT_VECS;
    srcp = W + (size_t)g * 8;
    dstp = Wb + (size_t)g * 8;
  } else if (gid < FEAT_VECS + W_VECS + CUR_VECS) {
    int g = gid - (FEAT_VECS + W_VECS);
    reinterpret_cast<int4*>(cursor)[g] = make_int4(0, 0, 0, 0);
    return;
  } else {
    return;
  }
  float4 a = reinterpret_cast<const float4*>(srcp)[0];
  float4 b = reinterpret_cast<const float4*>(srcp)[1];
  reinterpret_cast<ushort4*>(dstp)[0] =
      make_ushort4(f2bf(a.x), f2bf(a.y), f2bf(a.z), f2bf(a.w));
  reinterpret_cast<ushort4*>(dstp)[1] =
      make_ushort4(f2bf(b.x), f2bf(b.y), f2bf(b.z), f2bf(b.w));
}

// ---------------------------------------------------------------------------
// Pass 1: atomic-append edges into per-dst buckets. 2 edges per thread.
// ---------------------------------------------------------------------------
__global__ __launch_bounds__(256) void append_kernel(const int* __restrict__ src,
                                                     const int* __restrict__ dst,
                                                     const float* __restrict__ ew,
                                                     int* __restrict__ cursor,
                                                     int2* __restrict__ bucket) {
  int i = (blockIdx.x * 256 + threadIdx.x) * 2;
  if (i + 1 < N_EDGES) {
    int2 s2 = *reinterpret_cast<const int2*>(src + i);
    int2 d2 = *reinterpret_cast<const int2*>(dst + i);
    float2 w2 = *reinterpret_cast<const float2*>(ew + i);
    int pos0 = atomicAdd(&cursor[d2.x], 1);
    if (pos0 < CAP)
      bucket[(size_t)d2.x * CAP + pos0] = make_int2(s2.x, __float_as_int(w2.x));
    int pos1 = atomicAdd(&cursor[d2.y], 1);
    if (pos1 < CAP)
      bucket[(size_t)d2.y * CAP + pos1] = make_int2(s2.y, __float_as_int(w2.y));
  } else if (i < N_EDGES) {
    int d = dst[i];
    int pos = atomicAdd(&cursor[d], 1);
    if (pos < CAP)
      bucket[(size_t)d * CAP + pos] = make_int2(src[i], __float_as_int(ew[i]));
  }
}

// ---------------------------------------------------------------------------
// Pass 2 (FUSED): 1024-thread blocks (16 waves). Block b owns nodes
// [16b,16b+16). Phase A: wave w aggregates node 16b+w (FULL TLP: 625x16 =
// 10000 waves, fixing R13's 4x TLP loss) -> h_neigh bf16 to LDS only.
// Phase B: threads 0..511 stage the feat half. Phase C: wave w computes
// cols [16w,16w+16) via 16 MFMAs, B direct from L2-resident Wb.
// No cross-block deps; 625 x 16 = 10000 exact.
// ---------------------------------------------------------------------------
#define LPAD2 520   // A-tile LDS row stride in ushorts

__global__ __launch_bounds__(1024) void aggemm_kernel(
    const int* __restrict__ cursor, const int2* __restrict__ bucket,
    const unsigned short* __restrict__ featb, const unsigned short* __restrict__ Wb,
    const float* __restrict__ bias, float* __restrict__ out) {
  __shared__ unsigned short Ah[16][LPAD2];   // 16.6 KB

  int t = threadIdx.x;
  int w = t >> 6;          // 0..15
  int lane = t & 63;
  int node0 = blockIdx.x * 16;

  // ---------------- Phase A: one node per wave ----------------
  {
    int node = node0 + w;
    int cnt = cursor[node];
    int end = min(cnt, CAP);
    const int2* bk = bucket + (size_t)node * CAP;
    const unsigned short* fb = featb + (size_t)lane * 4;
    float acc0 = 0.f, acc1 = 0.f, acc2 = 0.f, acc3 = 0.f;
    int i = 0;

#define GATHER2(p, va, vb)                                                     \
    va = *reinterpret_cast<const ushort4*>(fb + (size_t)(p).x * D);            \
    vb = *reinterpret_cast<const ushort4*>(fb + (size_t)(p).z * D);
#define ACC1(v, wgt)                                                           \
    acc0 += bf2f((v).x) * (wgt); acc1 += bf2f((v).y) * (wgt);                  \
    acc2 += bf2f((v).z) * (wgt); acc3 += bf2f((v).w) * (wgt);
#define ACCP(p, va, vb)                                                        \
    { float wa_ = __int_as_float((p).y), wb_ = __int_as_float((p).w);          \
      ACC1(va, wa_) ACC1(vb, wb_) }

    for (; i + 8 <= end; i += 8) {
      int4 p0 = *reinterpret_cast<const int4*>(bk + i);
      int4 p1 = *reinterpret_cast<const int4*>(bk + i + 2);
      int4 p2 = *reinterpret_cast<const int4*>(bk + i + 4);
      int4 p3 = *reinterpret_cast<const int4*>(bk + i + 6);
      ushort4 v0, v1, v2, v3, v4, v5, v6, v7;
      GATHER2(p0, v0, v1) GATHER2(p1, v2, v3) GATHER2(p2, v4, v5) GATHER2(p3, v6, v7)
      ACCP(p0, v0, v1) ACCP(p1, v2, v3) ACCP(p2, v4, v5) ACCP(p3, v6, v7)
    }
    for (; i < end; ++i) {
      int2 sw = bk[i];
      ushort4 v = *reinterpret_cast<const ushort4*>(fb + (size_t)sw.x * D);
      float wgt = __int_as_float(sw.y);
      ACC1(v, wgt)
    }
#undef GATHER2
#undef ACC1
#undef ACCP

    float inv = 1.0f / fmaxf((float)cnt, 1.0f);
    ushort4 o = make_ushort4(f2bf(acc0 * inv), f2bf(acc1 * inv),
                             f2bf(acc2 * inv), f2bf(acc3 * inv));
    *reinterpret_cast<ushort4*>(&Ah[w][lane * 4]) = o;
  }

  // ---------------- Phase B: stage feat half of the A-tile ----------------
  if (t < 512) {
    int r = t >> 5;                // 16 rows x 32 vec8
    int v = t & 31;
    uint4 x = *reinterpret_cast<const uint4*>(featb + (size_t)(node0 + r) * D + v * 8);
    *reinterpret_cast<uint4*>(&Ah[r][D + v * 8]) = x;
  }
  __syncthreads();

  // ---------------- Phase C: wave w owns 16 cols ----------------
  int lhi = lane >> 4;   // 0..3
  int llo = lane & 15;   // 0..15
  f32x4 acc = (f32x4){0.f, 0.f, 0.f, 0.f};

  const unsigned short* wb0 = Wb + (size_t)(w * 16 + llo) * K_TOT + lhi * 8;
  #pragma unroll
  for (int ks = 0; ks < 16; ++ks) {
    bf16x8 a = *reinterpret_cast<const bf16x8*>(&Ah[llo][ks * 32 + lhi * 8]);
    bf16x8 b = *reinterpret_cast<const bf16x8*>(wb0 + ks * 32);
    acc = __builtin_amdgcn_mfma_f32_16x16x32_bf16(a, b, acc, 0, 0, 0);
  }

  int col = w * 16 + llo;
  float bv = bias[col];
  #pragma unroll
  for (int r = 0; r < 4; ++r) {
    out[(size_t)(node0 + lhi * 4 + r) * D + col] = acc[r] + bv;
  }
}

extern "C" void kernel_launch(void* const* d_in, const int* in_sizes, int n_in,
                              void* d_out, int out_size, void* d_ws, size_t ws_size,
                              hipStream_t stream) {
  const float* feat = (const float*)d_in[0];   // [10000,256]
  const float* ew   = (const float*)d_in[1];   // [320000,1]
  const float* W    = (const float*)d_in[2];   // [256,512]
  const float* bias = (const float*)d_in[3];   // [256]
  const int*   src  = (const int*)d_in[4];     // [320000]
  const int*   dst  = (const int*)d_in[5];     // [320000]
  float* out = (float*)d_out;                  // [10000,256]

  // workspace layout
  char* ws = (char*)d_ws;
  unsigned short* featb = (unsigned short*)ws; ws += (size_t)N_NODES * D * sizeof(unsigned short);   // 5.12 MB
  unsigned short* Wb    = (unsigned short*)ws; ws += (size_t)D * K_TOT * sizeof(unsigned short);     // 0.26 MB
  int* cursor   = (int*)ws;                    ws += N_NODES * sizeof(int);
  int2* bucket  = (int2*)ws;                   ws += (size_t)N_NODES * CAP * sizeof(int2);           // 10.24 MB

  tobf16_kernel<<<(FEAT_VECS + W_VECS + CUR_VECS + 255) / 256, 256, 0, stream>>>(
      feat, W, featb, Wb, cursor);
  append_kernel<<<(N_EDGES / 2 + 255) / 256, 256, 0, stream>>>(src, dst, ew, cursor, bucket);
  aggemm_kernel<<<N_NODES / 16, 1024, 0, stream>>>(cursor, bucket, featb, Wb, bias, out);
}